// Round 9
// baseline (100.104 us; speedup 1.0000x reference)
//
#include <hip/hip_runtime.h>

// DeepQNetwork fused forward:  x(B,15) -> onehot(36) -> 128 -> 512 -> 40
// Transposed MFMA scheme (features = M, batch rows = N), v_mfma_f32_16x16x32_bf16:
//   A frag (weights, prepacked fragment-linear in ws): lane = A[m=l16][k=quad*8+j]
//   B frag (activations): lane = act[row=l16][feat=quad*8+j] -> ds_read_b128
//   C/D: lane reg r = D[feat=quad*4+r][row=l16] -> pack 4 feats -> one ds_write_b64
// R9: break the per-chunk LDS write->wait->read turnaround (the R4-R8 invariant
// stall). h2 is double-buffered (two stride-72 regions per wave); chunk c-1's
// h2 reads + W4 MFMAs execute in the MIDDLE of chunk c's W2 MFMA bursts, so the
// lgkm drain is covered by ~600+ cyc of independent MFMA work (ILP, not TLP).
// Biases are folded into MFMA accumulator init (C-input) -- no epilogue adds.
// 2-wave blocks (64 rows/wave), grid 1024, LDS 36864B -> 4 blocks/CU, no barriers.

typedef short bf16x8 __attribute__((ext_vector_type(8)));
typedef float f32x4 __attribute__((ext_vector_type(4)));
typedef unsigned int u32;

#define NW1F 8192              // 16 frags  (8 mt * 2 ks)
#define NW2F 65536             // 128 frags (32 mt * 4 ks)
#define NW4F 24576             // 48 frags  (3 mt * 16 ks)
#define PACK_TOTAL (NW1F + NW2F + NW4F)   // 98304 shorts = 192 KB of ws
#define PACK_THREADS (PACK_TOTAL / 8)     // one b128 store per thread

__device__ __forceinline__ unsigned short f2bf(float f) {
  union { float f; unsigned u; } a; a.f = f;
  unsigned r = a.u + 0x7fffu + ((a.u >> 16) & 1u);
  return (unsigned short)(r >> 16);
}
// gfx950 packed convert, RNE: two f32 -> bf16x2 in one VALU op.
__device__ __forceinline__ u32 cvtpk(float lo, float hi) {
  u32 r;
  asm("v_cvt_pk_bf16_f32 %0, %1, %2" : "=v"(r) : "v"(lo), "v"(hi));
  return r;
}

// Prepack W1^T (128x64, K-pad 36->64), W2^T (512x128), W4^T (48x512, M-pad 40->48)
// as A-fragment-linear bf16: frag*512 + lane*8 + j = A[m=mt*16+l16][k=ks*32+quad*8+j].
__global__ void pack_weights(const float* __restrict__ W1,
                             const float* __restrict__ W2,
                             const float* __restrict__ W4,
                             unsigned short* __restrict__ wf) {
  int t = blockIdx.x * 256 + threadIdx.x;
  if (t >= PACK_THREADS) return;
  int fid = t >> 6, lane = t & 63;
  int l16 = lane & 15, quad = lane >> 4;
  float vals[8];
  if (fid < 16) {                       // W1: fid = mt*2+ks
    int mt = fid >> 1, ks = fid & 1;
    int m = mt * 16 + l16, k0 = ks * 32 + quad * 8;
#pragma unroll
    for (int j = 0; j < 8; ++j) { int k = k0 + j; vals[j] = (k < 36) ? W1[k * 128 + m] : 0.f; }
  } else if (fid < 144) {               // W2: fid-16 = mt*4+ks
    int f = fid - 16, mt = f >> 2, ks = f & 3;
    int m = mt * 16 + l16, k0 = ks * 32 + quad * 8;
#pragma unroll
    for (int j = 0; j < 8; ++j) vals[j] = W2[(k0 + j) * 512 + m];
  } else {                              // W4: fid-144 = mt*16+ks
    int f = fid - 144, mt = f >> 4, ks = f & 15;
    int m = mt * 16 + l16, k0 = ks * 32 + quad * 8;
#pragma unroll
    for (int j = 0; j < 8; ++j) vals[j] = (m < 40) ? W4[(k0 + j) * 40 + m] : 0.f;
  }
  u32 p[4];
#pragma unroll
  for (int j = 0; j < 4; ++j) p[j] = cvtpk(vals[2 * j], vals[2 * j + 1]);
  *(bf16x8*)(wf + (size_t)t * 8) = *(bf16x8*)p;
}

// 128 threads = 2 waves; each wave privately owns 64 rows (4 N-groups of 16).
// All LDS traffic is wave-private (DS ops of one wave complete in order);
// the kernel contains NO barriers at all.
__global__ __launch_bounds__(128, 2) void dqn_fused(
    const float* __restrict__ x,
    const unsigned short* __restrict__ wf,
    const float* __restrict__ b1,
    const float* __restrict__ b2,
    const float* __restrict__ b4,
    float* __restrict__ out) {
  // per wave: two 64x72-short regions. Region 0 = input -> h1 transit -> h2 even
  // chunks; region 1 = h2 odd chunks.
  __shared__ __align__(16) unsigned short sBuf[2 * 2 * 4608];  // 36864 B -> 4 blocks/CU

  const int tid  = threadIdx.x;
  const int lane = tid & 63;
  const int wave = tid >> 6;                     // 0 or 1
  const int quad = lane >> 4;
  const int l16  = lane & 15;
  const int row0 = blockIdx.x << 7;              // 128 rows per block
  const int lr0  = wave * 64;
  unsigned short* su = sBuf + wave * (2 * 4608); // wave-private

  const unsigned short* w2f = wf + NW1F;
  const unsigned short* w4f = wf + NW1F + NW2F;
  const unsigned short* w2p = w2f + lane * 8;    // frag f lives at w2p + f*512

  // software-pipeline prologue: W2 frag-quad 0 into registers now; its latency
  // overlaps input staging + the whole L1 GEMM.
  bf16x8 curW[4];
#pragma unroll
  for (int k = 0; k < 4; ++k) curW[k] = *(const bf16x8*)(w2p + (size_t)k * 512);

  // ---- stage 1: one-hot input rows in LDS (bf16), K padded 36->64; 1 row/lane ----
  {
    const float* xr = x + (size_t)(row0 + lr0 + lane) * 15;
    unsigned short* dst = su + lane * 72;
    bf16x8 z = {0, 0, 0, 0, 0, 0, 0, 0};
#pragma unroll
    for (int c = 8; c < 64; c += 8) *(bf16x8*)(dst + c) = z;   // zero cols 8..63
    u32 p[4];
#pragma unroll
    for (int i = 0; i < 4; ++i) p[i] = cvtpk(xr[2 * i], xr[2 * i + 1]);
    *(bf16x8*)dst = *(bf16x8*)p;                 // keep cols 0..7
    *(u32*)(dst + 8) = cvtpk(xr[8], xr[9]);      // keep cols 8..9
    dst[10] = f2bf(xr[10]);                      // keep col 10
    int hold = (int)xr[11]; hold = hold < 0 ? 0 : (hold > 3 ? 3 : hold);
    dst[11 + hold] = 0x3F80;                     // bf16 1.0
#pragma unroll
    for (int t = 0; t < 3; ++t) {
      int nx = (int)xr[12 + t] - 1; nx = nx < 0 ? 0 : (nx > 6 ? 6 : nx);
      dst[15 + t * 7 + nx] = 0x3F80;
    }
  }

  // ---- stage 2: h1^T = relu(W1^T @ inp^T + b1) -- bias in acc init; af1 to regs.
  bf16x8 ib[4][2];
#pragma unroll
  for (int rg = 0; rg < 4; ++rg)
#pragma unroll
    for (int ks = 0; ks < 2; ++ks)
      ib[rg][ks] = *(const bf16x8*)(su + (rg * 16 + l16) * 72 + ks * 32 + quad * 8);

  bf16x8 af1[4][4];   // [rg][ks_out]: h1 B-frags, filled per half
#pragma unroll
  for (int half = 0; half < 2; ++half) {
    bf16x8 wa[4][2];
#pragma unroll
    for (int mtl = 0; mtl < 4; ++mtl)
#pragma unroll
      for (int ks = 0; ks < 2; ++ks)
        wa[mtl][ks] = *(const bf16x8*)(
            wf + (size_t)(((half * 4 + mtl) * 2 + ks) * 64 + lane) * 8);

    f32x4 acc1[4][4];   // [mtl][rg]; init = b1 slice (fold bias)
#pragma unroll
    for (int mtl = 0; mtl < 4; ++mtl) {
      f32x4 bias = *(const f32x4*)(b1 + (half * 4 + mtl) * 16 + quad * 4);
#pragma unroll
      for (int rg = 0; rg < 4; ++rg) acc1[mtl][rg] = bias;
    }

#pragma unroll
    for (int mtl = 0; mtl < 4; ++mtl)
#pragma unroll
      for (int ks = 0; ks < 2; ++ks)
#pragma unroll
        for (int rg = 0; rg < 4; ++rg)
          acc1[mtl][rg] = __builtin_amdgcn_mfma_f32_16x16x32_bf16(wa[mtl][ks], ib[rg][ks], acc1[mtl][rg], 0, 0, 0);

#pragma unroll
    for (int mtl = 0; mtl < 4; ++mtl)
#pragma unroll
      for (int rg = 0; rg < 4; ++rg) {
        float v0 = fmaxf(acc1[mtl][rg][0], 0.f);
        float v1 = fmaxf(acc1[mtl][rg][1], 0.f);
        float v2 = fmaxf(acc1[mtl][rg][2], 0.f);
        float v3 = fmaxf(acc1[mtl][rg][3], 0.f);
        uint2 pk = {cvtpk(v0, v1), cvtpk(v2, v3)};
        *(uint2*)(su + (rg * 16 + l16) * 72 + mtl * 16 + quad * 4) = pk;
      }
#pragma unroll
    for (int rg = 0; rg < 4; ++rg)
#pragma unroll
      for (int ksl = 0; ksl < 2; ++ksl)
        af1[rg][half * 2 + ksl] =
            *(const bf16x8*)(su + (rg * 16 + l16) * 72 + ksl * 32 + quad * 8);
  }

  // accO init = b4 (pad cols clamp-addressed; masked at store)
  f32x4 accO[3][4];
#pragma unroll
  for (int mt3 = 0; mt3 < 3; ++mt3) {
    int colbase = mt3 * 16 + quad * 4;
    f32x4 bias = *(const f32x4*)(b4 + (colbase < 40 ? colbase : 36));
#pragma unroll
    for (int rg = 0; rg < 4; ++rg) accO[mt3][rg] = bias;
  }

  // ---- stage 3: register-pipelined W2 K-loop; W4(c-1) interleaved into chunk c ----
  bf16x8 w4r[2][3];     // W4 frags, consumed one chunk after load
  bf16x8 hp[8];         // h2(c-1) B-frags [ks3*4+rg]
  for (int chunk = 0; chunk < 8; ++chunk) {
    unsigned short* ubuf = su + (chunk & 1) * 4608;                 // write h2(c)
    const unsigned short* rbuf = su + ((chunk & 1) ^ 1) * 4608;     // read h2(c-1)
    if (chunk > 0) {    // W4 frags for chunk c-1 (used at mtl>=2)
      int pc = chunk - 1;
#pragma unroll
      for (int ks3 = 0; ks3 < 2; ++ks3)
#pragma unroll
        for (int mt3 = 0; mt3 < 3; ++mt3)
          w4r[ks3][mt3] = *(const bf16x8*)(
              w4f + (size_t)((mt3 * 16 + pc * 2 + ks3) * 64 + lane) * 8);
    }
    f32x4 b2v[4];
#pragma unroll
    for (int mtl = 0; mtl < 4; ++mtl)
      b2v[mtl] = *(const f32x4*)(b2 + chunk * 64 + mtl * 16 + quad * 4);

#pragma unroll
    for (int mtl = 0; mtl < 4; ++mtl) {
      // prefetch next frag-quad (one full mtl-step ahead)
      int fb = chunk * 16 + mtl * 4 + 4;
      if (fb >= 128) fb = 0;             // harmless redundant load on last step
      bf16x8 nxtW[4];
#pragma unroll
      for (int k = 0; k < 4; ++k)
        nxtW[k] = *(const bf16x8*)(w2p + (size_t)(fb + k) * 512);

      f32x4 acc2[4];                     // [rg]; init = b2 slice (fold bias)
#pragma unroll
      for (int rg = 0; rg < 4; ++rg) acc2[rg] = b2v[mtl];
#pragma unroll
      for (int ks = 0; ks < 4; ++ks)
#pragma unroll
        for (int rg = 0; rg < 4; ++rg)
          acc2[rg] = __builtin_amdgcn_mfma_f32_16x16x32_bf16(curW[ks], af1[rg][ks], acc2[rg], 0, 0, 0);

      // interleave previous chunk's W4 stage between W2 MFMA bursts:
      if (chunk > 0 && mtl == 1) {       // h2(c-1) reads: writes were ~2 bursts ago
#pragma unroll
        for (int ks3 = 0; ks3 < 2; ++ks3)
#pragma unroll
          for (int rg = 0; rg < 4; ++rg)
            hp[ks3 * 4 + rg] = *(const bf16x8*)(
                rbuf + (rg * 16 + l16) * 72 + ks3 * 32 + quad * 8);
      }
      if (chunk > 0 && mtl == 2) {
#pragma unroll
        for (int mt3 = 0; mt3 < 3; ++mt3)
#pragma unroll
          for (int rg = 0; rg < 4; ++rg)
            accO[mt3][rg] = __builtin_amdgcn_mfma_f32_16x16x32_bf16(w4r[0][mt3], hp[rg], accO[mt3][rg], 0, 0, 0);
      }
      if (chunk > 0 && mtl == 3) {
#pragma unroll
        for (int mt3 = 0; mt3 < 3; ++mt3)
#pragma unroll
          for (int rg = 0; rg < 4; ++rg)
            accO[mt3][rg] = __builtin_amdgcn_mfma_f32_16x16x32_bf16(w4r[1][mt3], hp[4 + rg], accO[mt3][rg], 0, 0, 0);
      }

      // relu + pack -> h2(c) cols mtl*16 + quad*4 (b64 writes into ubuf)
#pragma unroll
      for (int rg = 0; rg < 4; ++rg) {
        float v0 = fmaxf(acc2[rg][0], 0.f);
        float v1 = fmaxf(acc2[rg][1], 0.f);
        float v2 = fmaxf(acc2[rg][2], 0.f);
        float v3 = fmaxf(acc2[rg][3], 0.f);
        uint2 pk = {cvtpk(v0, v1), cvtpk(v2, v3)};
        *(uint2*)(ubuf + (rg * 16 + l16) * 72 + mtl * 16 + quad * 4) = pk;
      }
#pragma unroll
      for (int k = 0; k < 4; ++k) curW[k] = nxtW[k];
    }
  }

  // ---- tail: W4 stage for chunk 7 (h2 in region (7&1)=1) ----
  {
    const unsigned short* rbuf = su + 4608;
#pragma unroll
    for (int ks3 = 0; ks3 < 2; ++ks3)
#pragma unroll
      for (int mt3 = 0; mt3 < 3; ++mt3)
        w4r[ks3][mt3] = *(const bf16x8*)(
            w4f + (size_t)((mt3 * 16 + 7 * 2 + ks3) * 64 + lane) * 8);
#pragma unroll
    for (int ks3 = 0; ks3 < 2; ++ks3) {
#pragma unroll
      for (int rg = 0; rg < 4; ++rg) {
        bf16x8 h = *(const bf16x8*)(rbuf + (rg * 16 + l16) * 72 + ks3 * 32 + quad * 8);
#pragma unroll
        for (int mt3 = 0; mt3 < 3; ++mt3)
          accO[mt3][rg] = __builtin_amdgcn_mfma_f32_16x16x32_bf16(w4r[ks3][mt3], h, accO[mt3][rg], 0, 0, 0);
      }
    }
  }

  // ---- epilogue: bias already in accO; float4 stores (4 consecutive out-cols) ----
#pragma unroll
  for (int mt3 = 0; mt3 < 3; ++mt3) {
    int colbase = mt3 * 16 + quad * 4;
    if (colbase < 40) {                      // drops pad cols 40..47
#pragma unroll
      for (int rg = 0; rg < 4; ++rg) {
        size_t row = (size_t)(row0 + lr0 + rg * 16 + l16);
        *(f32x4*)(out + row * 40 + colbase) = accO[mt3][rg];
      }
    }
  }
}

extern "C" void kernel_launch(void* const* d_in, const int* in_sizes, int n_in,
                              void* d_out, int out_size, void* d_ws, size_t ws_size,
                              hipStream_t stream) {
  const float* x  = (const float*)d_in[0];
  const float* W1 = (const float*)d_in[1];
  const float* b1 = (const float*)d_in[2];
  const float* W2 = (const float*)d_in[3];
  const float* b2 = (const float*)d_in[4];
  const float* W4 = (const float*)d_in[5];
  const float* b4 = (const float*)d_in[6];
  float* out = (float*)d_out;
  unsigned short* wf = (unsigned short*)d_ws;   // 192 KB of ws

  int B = in_sizes[0] / 15;

  hipLaunchKernelGGL(pack_weights, dim3((PACK_THREADS + 255) / 256), dim3(256), 0, stream,
                     W1, W2, W4, wf);
  hipLaunchKernelGGL(dqn_fused, dim3(B / 128), dim3(128), 0, stream,
                     x, wf, b1, b2, b4, out);
}